// Round 3
// baseline (367.491 us; speedup 1.0000x reference)
//
#include <hip/hip_runtime.h>
#include <hip/hip_bf16.h>
#include <math.h>

typedef __bf16 bf16;
typedef __bf16 bf16x8 __attribute__((ext_vector_type(8)));
typedef __bf16 bf16x4 __attribute__((ext_vector_type(4)));
typedef float  f32x4  __attribute__((ext_vector_type(4)));

#define D_MODEL 384
#define HID     1536
#define NSEQ    1024
#define ROWS    16384
#define HEADS   8
#define DH      48
#define SCALE   0.14433756729740643f // 48^-0.5
#define LOG2E   1.4426950408889634f
#define QSCALE  (SCALE * LOG2E)      // folded into Q pack: scores in log2 units
#define M0      (-8.0f * LOG2E)      // fixed softmax max (log2 units), acc init
// bias table: |dy| in [0,31] x (dx+31) in [0,62] -> 2016 bf16 entries/head
#define BT2_N   2016
#define BT2_P   2048                 // padded to 4096 B per head
// packed KV tile geometry: [64 rows][72 cols] bf16 = 9216 B per tile
#define KVT     4608                 // elems per tile
#define QP_BH   (NSEQ * DH)          // 49152 elems per bh in Qpack
#define KP_BH   (16 * KVT)           // 73728 elems per bh in K/Vpack

__device__ __forceinline__ void gload16(const void* g, void* l) {
    __builtin_amdgcn_global_load_lds((const __attribute__((address_space(1))) void*)g,
                                     (__attribute__((address_space(3))) void*)l, 16, 0, 0);
}

// tanh-form GELU: max |err| vs exact erf-GELU ~1e-3 (below bf16 quantization)
__device__ __forceinline__ float fast_gelu(float x) {
    float u = 0.7978845608f * fmaf(0.044715f * x * x, x, x);
    float e = __expf(2.f * u);
    float t = 1.f - 2.f * __builtin_amdgcn_rcpf(e + 1.f);   // tanh(u)
    return 0.5f * x * (1.f + t);
}

// ---------------------------------------------------------------------------
// Bias prep: Btab[h][|dy|*63 + dx+31] = bias_table[ceil(dist)][h] * log2(e)
// (bf16; dist is symmetric in dy so only |dy| rows are stored)
// ---------------------------------------------------------------------------
__global__ __launch_bounds__(256)
void bias_prep_kernel(const float* __restrict__ bias_table, bf16* __restrict__ Btab)
{
    int idx = blockIdx.x * 256 + threadIdx.x;
    if (idx >= BT2_N) return;
    int dy = idx / 63, dx = idx % 63 - 31;
    int s2 = dy * dy + dx * dx;
    int r = (int)ceilf(sqrtf((float)s2));
    while (r * r < s2) ++r;
    while (r > 0 && (r - 1) * (r - 1) >= s2) --r;
#pragma unroll
    for (int h = 0; h < HEADS; ++h)
        Btab[h * BT2_P + idx] = (bf16)(bias_table[r * HEADS + h] * LOG2E);
}

// ---------------------------------------------------------------------------
// Pack init (each launch; ws re-poisoned): zero Kpack pad cols 48..71,
// ones in Vpack rows 48..63 (the l-sum rows).
// ---------------------------------------------------------------------------
__global__ __launch_bounds__(256)
void pack_init_kernel(bf16* __restrict__ Kp, bf16* __restrict__ Vp)
{
    const int bid = blockIdx.x, tid = threadIdx.x;
    if (bid < 512) {                       // 131072 K-rows, pad cols 48..71
        int row = bid * 256 + tid;
        bf16x8 z = {};
        bf16* p = Kp + (size_t)row * 72 + 48;
        *(bf16x8*)(p) = z;  *(bf16x8*)(p + 8) = z;  *(bf16x8*)(p + 16) = z;
    } else {                               // 32768 V ones-rows
        int idx = (bid - 512) * 256 + tid;
        int tile = idx >> 4, rr = idx & 15;
        bf16 o = (bf16)1.f;
        bf16x8 ones = {o, o, o, o, o, o, o, o};
        bf16* p = Vp + (size_t)tile * KVT + (48 + rr) * 72;
#pragma unroll
        for (int c = 0; c < 9; ++c) *(bf16x8*)(p + c * 8) = ones;
    }
}

// ---------------------------------------------------------------------------
// Weight prep: out[n][k] = (bf16)in[k][n].
// ---------------------------------------------------------------------------
__global__ __launch_bounds__(256)
void wtrans_kernel(const float* __restrict__ in, bf16* __restrict__ out, int K, int N)
{
    __shared__ float T[64][65];
    const int k0 = blockIdx.y * 64, n0 = blockIdx.x * 64;
    const int rr = threadIdx.x >> 4, rc = threadIdx.x & 15;
#pragma unroll
    for (int i = 0; i < 4; ++i) {
        float4 v = *(const float4*)(in + (size_t)(k0 + rr + i * 16) * N + n0 + rc * 4);
        T[rr + i * 16][rc * 4 + 0] = v.x;  T[rr + i * 16][rc * 4 + 1] = v.y;
        T[rr + i * 16][rc * 4 + 2] = v.z;  T[rr + i * 16][rc * 4 + 3] = v.w;
    }
    __syncthreads();
#pragma unroll
    for (int i = 0; i < 4; ++i) {
        int n = rr + i * 16, kc = rc * 4;
        bf16x4 o;
        o[0] = (bf16)T[kc + 0][n];  o[1] = (bf16)T[kc + 1][n];
        o[2] = (bf16)T[kc + 2][n];  o[3] = (bf16)T[kc + 3][n];
        *(bf16x4*)(out + (size_t)(n0 + n) * K + k0 + kc) = o;
    }
}

// ---------------------------------------------------------------------------
// LayerNorm: one wave per row of 384. f32 in -> bf16 out.
// ---------------------------------------------------------------------------
__global__ __launch_bounds__(64)
void ln_kernel(const float* __restrict__ x, const float* __restrict__ w,
               const float* __restrict__ b, bf16* __restrict__ out)
{
    int row  = blockIdx.x;
    int lane = threadIdx.x;
    const float* xr = x + (size_t)row * D_MODEL;

    float v[6], s = 0.f, ss = 0.f;
#pragma unroll
    for (int i = 0; i < 6; ++i) {
        v[i] = xr[lane + i * 64];
        s  += v[i];
        ss += v[i] * v[i];
    }
#pragma unroll
    for (int off = 32; off; off >>= 1) {
        s  += __shfl_xor(s,  off);
        ss += __shfl_xor(ss, off);
    }
    float mu   = s * (1.f / D_MODEL);
    float var  = ss * (1.f / D_MODEL) - mu * mu;
    float rstd = rsqrtf(var + 1e-5f);

    bf16* orow = out + (size_t)row * D_MODEL;
#pragma unroll
    for (int i = 0; i < 6; ++i) {
        int c = lane + i * 64;
        orow[c] = (bf16)((v[i] - mu) * rstd * w[c] + b[c]);
    }
}

// ---------------------------------------------------------------------------
// GEMM: C[M,N] = A[M,K] @ BT[N,K]^T, bf16, 128x128 tile, BK=64, XCD swizzle.
// EPI 1: +bias +f32 res -> f32.  EPI 2: +bias, fast GELU -> bf16.
// EPI 3: scatter to packed Q/K/V attn layouts (QSCALE folded into Q).
// ---------------------------------------------------------------------------
template<int EPI, typename CT>
__global__ __launch_bounds__(256)
void gemm3_kernel(const bf16* __restrict__ A, const bf16* __restrict__ BT,
                  CT* __restrict__ C, const float* __restrict__ bias,
                  const float* __restrict__ res, int nxblk, int Nn, int K,
                  bf16* __restrict__ qp, bf16* __restrict__ kp, bf16* __restrict__ vp)
{
    __shared__ alignas(16) bf16 As[128][64];
    __shared__ alignas(16) bf16 Bs[128][64];

    const int bid  = blockIdx.x;
    const int xcd  = bid & 7;
    const int slot = bid >> 3;
    const int yy   = slot / nxblk;
    const int m0   = (yy * 8 + xcd) * 128;
    const int n0   = (slot - yy * nxblk) * 128;

    const int tid  = threadIdx.x;
    const int w    = tid >> 6;
    const int lane = tid & 63;
    const int quad = lane >> 4;
    const int l16  = lane & 15;

    const int srow = lane >> 3;          // 0..7
    const int scol = (lane & 7) * 8;     // 0..56

    f32x4 acc[4][4] = {};

    for (int kt = 0; kt < K; kt += 64) {
        __syncthreads();
#pragma unroll
        for (int c = 0; c < 4; ++c) {
            const int ch = w * 4 + c;
            gload16(A  + (size_t)(m0 + ch * 8 + srow) * K + kt + scol, &As[ch * 8][0]);
            gload16(BT + (size_t)(n0 + ch * 8 + srow) * K + kt + scol, &Bs[ch * 8][0]);
        }
        __syncthreads();

#pragma unroll
        for (int kk = 0; kk < 2; ++kk) {
            bf16x8 af[4], bfr[4];
#pragma unroll
            for (int mt = 0; mt < 4; ++mt)
                af[mt] = *(const bf16x8*)(&As[(w & 1) * 64 + mt * 16 + l16][kk * 32 + quad * 8]);
#pragma unroll
            for (int nt = 0; nt < 4; ++nt)
                bfr[nt] = *(const bf16x8*)(&Bs[(w >> 1) * 64 + nt * 16 + l16][kk * 32 + quad * 8]);
#pragma unroll
            for (int mt = 0; mt < 4; ++mt)
#pragma unroll
                for (int nt = 0; nt < 4; ++nt)
                    acc[mt][nt] = __builtin_amdgcn_mfma_f32_16x16x32_bf16(
                        af[mt], bfr[nt], acc[mt][nt], 0, 0, 0);
        }
    }

#pragma unroll
    for (int mt = 0; mt < 4; ++mt) {
#pragma unroll
        for (int nt = 0; nt < 4; ++nt) {
            const int c0 = n0 + (w >> 1) * 64 + nt * 16;   // wave-uniform
            const int c  = c0 + l16;
            float bi = (EPI == 1 || EPI == 2) ? bias[c] : 0.f;
#pragma unroll
            for (int r = 0; r < 4; ++r) {
                int row = m0 + (w & 1) * 64 + mt * 16 + quad * 4 + r;
                float v = acc[mt][nt][r] + bi;
                if (EPI == 1) {
                    v += res[(size_t)row * Nn + c];
                    C[(size_t)row * Nn + c] = (CT)v;
                } else if (EPI == 2) {
                    v = fast_gelu(v);
                    C[(size_t)row * Nn + c] = (CT)v;
                } else { // EPI 3: packed QKV scatter
                    int b   = row >> 10, seq = row & 1023;
                    if (c0 < 384) {            // Q (scaled to log2 units)
                        int h = c / 48, d = c - h * 48;
                        qp[(size_t)(b * 8 + h) * QP_BH + seq * 48 + d] = (bf16)(v * QSCALE);
                    } else if (c0 < 768) {     // K
                        int ck = c - 384;
                        int h = ck / 48, d = ck - h * 48;
                        kp[(size_t)(b * 8 + h) * KP_BH + (seq >> 6) * KVT
                           + (seq & 63) * 72 + d] = (bf16)v;
                    } else {                   // V transposed
                        int cv = c - 768;
                        int h = cv / 48, d = cv - h * 48;
                        vp[(size_t)(b * 8 + h) * KP_BH + (seq >> 6) * KVT
                           + d * 72 + (seq & 63)] = (bf16)v;
                    }
                }
            }
        }
    }
}

// ---------------------------------------------------------------------------
// MFMA flash attention v6: round-0 dataflow + 4 blocks/CU (LDS 40960 B).
// No waves-per-EU hint (compiler schedules for ILP). Bias gathers for the
// whole tile are hoisted to the top of the tile loop (latency hides under
// K/V staging + QK^T MFMAs). Softmax in log2 units, acc init M0.
// ---------------------------------------------------------------------------
__global__ __launch_bounds__(256)
void attn_kernel(const bf16* __restrict__ Qp, const bf16* __restrict__ Kp,
                 const bf16* __restrict__ Vp, const bf16* __restrict__ Btab,
                 bf16* __restrict__ out)
{
    __shared__ alignas(16) bf16 Ks[64][72];        // [key][dh pad64; 48..63 zero]
    __shared__ alignas(16) bf16 Vs[64][72];        // [dh][key]; rows 48..63 ones
    __shared__ alignas(16) bf16 Ps[4][2][16][72];  // [wave][strip][query][key]
    __shared__ alignas(16) bf16 B2h[BT2_P];        // bias, bf16, log2 units

    const int bid  = blockIdx.x;
    const int xcd  = bid & 7;
    const int slot = bid >> 3;
    const int qc   = slot & 7;
    const int bh   = (slot >> 3) * 8 + xcd;        // 0..127
    const int q0   = qc * 128;
    const int tid  = threadIdx.x;
    const int wave = tid >> 6;
    const int lane = tid & 63;
    const int quad = lane >> 4;
    const int l16  = lane & 15;
    const int b    = bh >> 3, h = bh & 7;

    // stage bias table (4096 B): exactly one gload16 per thread
    gload16((const char*)(Btab + (size_t)h * BT2_P) + tid * 16,
            (char*)B2h + wave * 1024);

    // Q fragments for 2 strips (B-operand), QSCALE pre-applied in Qpack
    bf16x8 qf0[2], qf1[2];
    int qy[2], qxp[2];
#pragma unroll
    for (int s = 0; s < 2; ++s) {
        int qrow = q0 + s * 64 + wave * 16 + l16;
        const bf16* qptr = Qp + (size_t)bh * QP_BH + qrow * 48;
        qf0[s] = *(const bf16x8*)(qptr + quad * 8);
#pragma unroll
        for (int c = 0; c < 8; ++c) qf1[s][c] = (bf16)0.f;
        if (quad < 2) qf1[s] = *(const bf16x8*)(qptr + 32 + quad * 8);
        qy[s]  = qrow >> 5;
        qxp[s] = (qrow & 31) + 31;
    }

    // B2h staged (and Q loads complete) before the hoisted tile-0 bias reads
    __syncthreads();

    f32x4 o_acc[2][4] = {};   // [strip][0..2 = O dims, 3 = l]

    for (int t = 0; t < 16; ++t) {
        const int n0 = t * 64;
        const bf16* kbase = Kp + (size_t)(bh * 16 + t) * KVT;
        const bf16* vbase = Vp + (size_t)(bh * 16 + t) * KVT;

        // hoisted bias gather for this tile: 32 values into 16 packed regs;
        // LDS-read latency hides under staging + QK^T below
        bf16x4 bvh[2][4];
#pragma unroll
        for (int s = 0; s < 2; ++s)
#pragma unroll
            for (int nt = 0; nt < 4; ++nt) {
                const int j0 = n0 + nt * 16 + quad * 4;
                int dy  = qy[s] - (j0 >> 5);
                int iay = dy < 0 ? -dy : dy;
                const int ib0 = iay * 63 + qxp[s] - (j0 & 31);
#pragma unroll
                for (int r = 0; r < 4; ++r)
                    bvh[s][nt][r] = B2h[ib0 - r];
            }

        __syncthreads();
        for (int c = 0; c < 18; ++c) {
            if ((c & 3) == wave) {
                if (c < 9) gload16(kbase + c * 512 + lane * 8, (bf16*)Ks + c * 512);
                else       gload16(vbase + (c - 9) * 512 + lane * 8, (bf16*)Vs + (c - 9) * 512);
            }
        }
        __syncthreads();

        // S^T = K @ Q^T: D[key=quad*4+r][query=l16], K-frags shared by strips
        f32x4 sa[2][4];
#pragma unroll
        for (int s = 0; s < 2; ++s)
#pragma unroll
            for (int nt = 0; nt < 4; ++nt)
                sa[s][nt] = (f32x4){M0, M0, M0, M0};
#pragma unroll
        for (int nt = 0; nt < 4; ++nt) {
            bf16x8 a0 = *(const bf16x8*)(&Ks[nt * 16 + l16][quad * 8]);
            bf16x8 a1 = *(const bf16x8*)(&Ks[nt * 16 + l16][32 + quad * 8]);
#pragma unroll
            for (int s = 0; s < 2; ++s) {
                sa[s][nt] = __builtin_amdgcn_mfma_f32_16x16x32_bf16(a0, qf0[s], sa[s][nt], 0, 0, 0);
                sa[s][nt] = __builtin_amdgcn_mfma_f32_16x16x32_bf16(a1, qf1[s], sa[s][nt], 0, 0, 0);
            }
        }

        // p = exp2(s + bias), both strips (batched writes)
#pragma unroll
        for (int s = 0; s < 2; ++s)
#pragma unroll
            for (int nt = 0; nt < 4; ++nt) {
                bf16x4 pk;
#pragma unroll
                for (int r = 0; r < 4; ++r)
                    pk[r] = (bf16)__builtin_amdgcn_exp2f(sa[s][nt][r] + (float)bvh[s][nt][r]);
                *(bf16x4*)(&Ps[wave][s][l16][nt * 16 + quad * 4]) = pk;
            }

        // O += P @ V; V-frags shared by strips; d=3 row accumulates l
#pragma unroll
        for (int kk = 0; kk < 2; ++kk) {
            bf16x8 vf[4];
#pragma unroll
            for (int d = 0; d < 4; ++d)
                vf[d] = *(const bf16x8*)(&Vs[d * 16 + l16][kk * 32 + quad * 8]);
#pragma unroll
            for (int s = 0; s < 2; ++s) {
                bf16x8 pf = *(const bf16x8*)(&Ps[wave][s][l16][kk * 32 + quad * 8]);
#pragma unroll
                for (int d = 0; d < 4; ++d)
                    o_acc[s][d] = __builtin_amdgcn_mfma_f32_16x16x32_bf16(
                        pf, vf[d], o_acc[s][d], 0, 0, 0);
            }
        }
    }

    // epilogue
#pragma unroll
    for (int s = 0; s < 2; ++s)
#pragma unroll
        for (int r = 0; r < 4; ++r) {
            float inv = 1.f / o_acc[s][3][r];
            int row = q0 + s * 64 + wave * 16 + quad * 4 + r;
            bf16* orow = out + ((size_t)b * NSEQ + row) * D_MODEL + h * DH;
#pragma unroll
            for (int d = 0; d < 3; ++d)
                orow[d * 16 + l16] = (bf16)(o_acc[s][d][r] * inv);
        }
}

// ---------------------------------------------------------------------------
extern "C" void kernel_launch(void* const* d_in, const int* in_sizes, int n_in,
                              void* d_out, int out_size, void* d_ws, size_t ws_size,
                              hipStream_t stream)
{
    const float* x          = (const float*)d_in[0];
    const float* ln1_w      = (const float*)d_in[1];
    const float* ln1_b      = (const float*)d_in[2];
    const float* w_qkv      = (const float*)d_in[3];
    const float* bias_table = (const float*)d_in[4];
    const float* w_out      = (const float*)d_in[5];
    const float* b_out      = (const float*)d_in[6];
    const float* ln2_w      = (const float*)d_in[7];
    const float* ln2_b      = (const float*)d_in[8];
    const float* w1         = (const float*)d_in[9];
    const float* b1         = (const float*)d_in[10];
    const float* w2         = (const float*)d_in[11];
    const float* b2         = (const float*)d_in[12];
    float* out = (float*)d_out;

    bf16* regA  = (bf16*)d_ws;                    // 25.17M elems: packs, later gelu
    bf16* Qpack = regA;                           // [128][1024][48]     6.29M
    bf16* Kpack = regA + 6291456;                 // [128][16][64][72]   9.44M
    bf16* Vpack = regA + 15728640;                // [128][16][64][72]   9.44M
    bf16* regB  = regA + (size_t)ROWS * HID;      // [16384][384]
    bf16* wqkvT = regB + (size_t)ROWS * D_MODEL;  // [1152][384]
    bf16* woutT = wqkvT + 1152 * 384;             // [384][384]
    bf16* w1T   = woutT + 384 * 384;              // [1536][384]
    bf16* w2T   = w1T + 1536 * 384;               // [384][1536]
    bf16* Btab  = w2T + 384 * 1536;               // [8][2048] bf16
    float* x1   = out;                            // residual in d_out (f32)

    bias_prep_kernel<<<(BT2_N + 255) / 256, 256, 0, stream>>>(bias_table, Btab);
    pack_init_kernel<<<640, 256, 0, stream>>>(Kpack, Vpack);
    wtrans_kernel<<<dim3(1152 / 64, 384 / 64), 256, 0, stream>>>(w_qkv, wqkvT, 384, 1152);
    wtrans_kernel<<<dim3(384 / 64, 384 / 64), 256, 0, stream>>>(w_out, woutT, 384, 384);
    wtrans_kernel<<<dim3(1536 / 64, 384 / 64), 256, 0, stream>>>(w1, w1T, 384, 1536);
    wtrans_kernel<<<dim3(384 / 64, 1536 / 64), 256, 0, stream>>>(w2, w2T, 1536, 384);

    // 1. LN1 -> regB
    ln_kernel<<<ROWS, 64, 0, stream>>>(x, ln1_w, ln1_b, regB);
    // 2. qkv GEMM -> packed Q/K/V (EPI3)
    gemm3_kernel<3, bf16><<<(1152 / 128) * (ROWS / 128), 256, 0, stream>>>(
        regB, wqkvT, (bf16*)nullptr, nullptr, nullptr, 1152 / 128, 1152, D_MODEL,
        Qpack, Kpack, Vpack);
    // 3. attention -> regB
    attn_kernel<<<1024, 256, 0, stream>>>(Qpack, Kpack, Vpack, Btab, regB);
    // 4. x1 = attn @ w_out + b_out + x -> d_out (f32)
    gemm3_kernel<1, float><<<(D_MODEL / 128) * (ROWS / 128), 256, 0, stream>>>(
        regB, woutT, x1, b_out, x, D_MODEL / 128, D_MODEL, D_MODEL,
        nullptr, nullptr, nullptr);
    // 5. LN2 -> regB
    ln_kernel<<<ROWS, 64, 0, stream>>>(x1, ln2_w, ln2_b, regB);
    // 6. gelu(h2 @ w1 + b1) -> regA (packs dead now)
    gemm3_kernel<2, bf16><<<(HID / 128) * (ROWS / 128), 256, 0, stream>>>(
        regB, w1T, regA, b1, nullptr, HID / 128, HID, D_MODEL,
        nullptr, nullptr, nullptr);
    // 7. out = gelu @ w2 + b2 + x1
    gemm3_kernel<1, float><<<(D_MODEL / 128) * (ROWS / 128), 256, 0, stream>>>(
        regA, w2T, out, b2, x1, D_MODEL / 128, D_MODEL, HID,
        nullptr, nullptr, nullptr);
}

// Round 4
// 328.972 us; speedup vs baseline: 1.1171x; 1.1171x over previous
//
#include <hip/hip_runtime.h>
#include <hip/hip_bf16.h>
#include <math.h>

typedef __bf16 bf16;
typedef __bf16 bf16x8 __attribute__((ext_vector_type(8)));
typedef __bf16 bf16x4 __attribute__((ext_vector_type(4)));
typedef __bf16 bf16x2 __attribute__((ext_vector_type(2)));
typedef float  f32x4  __attribute__((ext_vector_type(4)));

#define D_MODEL 384
#define HID     1536
#define NSEQ    1024
#define ROWS    16384
#define HEADS   8
#define DH      48
#define SCALE   0.14433756729740643f // 48^-0.5
#define MFIX    8.0f                 // fixed softmax max (scores bounded ~6.5)
#define BTAB_N  3969                 // 63*63
#define BTAB_P  3972                 // padded to 16B multiple (f32)
// packed KV tile geometry: [64 rows][72 cols] bf16 = 9216 B per tile
#define KVT     4608                 // elems per tile
#define QP_BH   (NSEQ * DH)          // 49152 elems per bh in Qpack
#define KP_BH   (16 * KVT)           // 73728 elems per bh in K/Vpack

__device__ __forceinline__ void gload16(const void* g, void* l) {
    __builtin_amdgcn_global_load_lds((const __attribute__((address_space(1))) void*)g,
                                     (__attribute__((address_space(3))) void*)l, 16, 0, 0);
}

// tanh-form GELU: max |err| vs exact erf-GELU ~1e-3 (below bf16 quantization)
__device__ __forceinline__ float fast_gelu(float x) {
    float u = 0.7978845608f * fmaf(0.044715f * x * x, x, x);
    float e = __expf(2.f * u);
    float t = 1.f - 2.f * __builtin_amdgcn_rcpf(e + 1.f);   // tanh(u)
    return 0.5f * x * (1.f + t);
}

// ---------------------------------------------------------------------------
// Bias prep: Btab[h][idx(dy,dx)] = bias_table[ceil(dist)][h] - MFIX  (f32)
// ---------------------------------------------------------------------------
__global__ __launch_bounds__(256)
void bias_prep_kernel(const float* __restrict__ bias_table, float* __restrict__ Btab)
{
    int idx = blockIdx.x * 256 + threadIdx.x;
    if (idx >= BTAB_N) return;
    int dy = idx / 63 - 31, dx = idx % 63 - 31;
    int s2 = dy * dy + dx * dx;
    int r = (int)ceilf(sqrtf((float)s2));
    while (r * r < s2) ++r;
    while (r > 0 && (r - 1) * (r - 1) >= s2) --r;
#pragma unroll
    for (int h = 0; h < HEADS; ++h)
        Btab[h * BTAB_P + idx] = bias_table[r * HEADS + h] - MFIX;
}

// ---------------------------------------------------------------------------
// Pack init (each launch; ws re-poisoned): zero Kpack pad cols 48..71,
// ones in Vpack rows 48..63 (the l-sum rows).
// ---------------------------------------------------------------------------
__global__ __launch_bounds__(256)
void pack_init_kernel(bf16* __restrict__ Kp, bf16* __restrict__ Vp)
{
    const int bid = blockIdx.x, tid = threadIdx.x;
    if (bid < 512) {                       // 131072 K-rows, pad cols 48..71
        int row = bid * 256 + tid;
        bf16x8 z = {};
        bf16* p = Kp + (size_t)row * 72 + 48;
        *(bf16x8*)(p) = z;  *(bf16x8*)(p + 8) = z;  *(bf16x8*)(p + 16) = z;
    } else {                               // 32768 V ones-rows
        int idx = (bid - 512) * 256 + tid;
        int tile = idx >> 4, rr = idx & 15;
        bf16 o = (bf16)1.f;
        bf16x8 ones = {o, o, o, o, o, o, o, o};
        bf16* p = Vp + (size_t)tile * KVT + (48 + rr) * 72;
#pragma unroll
        for (int c = 0; c < 9; ++c) *(bf16x8*)(p + c * 8) = ones;
    }
}

// ---------------------------------------------------------------------------
// Weight prep: out[n][k] = (bf16)in[k][n].
// ---------------------------------------------------------------------------
__global__ __launch_bounds__(256)
void wtrans_kernel(const float* __restrict__ in, bf16* __restrict__ out, int K, int N)
{
    __shared__ float T[64][65];
    const int k0 = blockIdx.y * 64, n0 = blockIdx.x * 64;
    const int rr = threadIdx.x >> 4, rc = threadIdx.x & 15;
#pragma unroll
    for (int i = 0; i < 4; ++i) {
        float4 v = *(const float4*)(in + (size_t)(k0 + rr + i * 16) * N + n0 + rc * 4);
        T[rr + i * 16][rc * 4 + 0] = v.x;  T[rr + i * 16][rc * 4 + 1] = v.y;
        T[rr + i * 16][rc * 4 + 2] = v.z;  T[rr + i * 16][rc * 4 + 3] = v.w;
    }
    __syncthreads();
#pragma unroll
    for (int i = 0; i < 4; ++i) {
        int n = rr + i * 16, kc = rc * 4;
        bf16x4 o;
        o[0] = (bf16)T[kc + 0][n];  o[1] = (bf16)T[kc + 1][n];
        o[2] = (bf16)T[kc + 2][n];  o[3] = (bf16)T[kc + 3][n];
        *(bf16x4*)(out + (size_t)(n0 + n) * K + k0 + kc) = o;
    }
}

// ---------------------------------------------------------------------------
// LayerNorm: 4 rows per 256-thread block, one wave per row of 384.
// float2 (8B/lane) vectorized loads, bf16x2 stores. f32 in -> bf16 out.
// ---------------------------------------------------------------------------
__global__ __launch_bounds__(256)
void ln_kernel(const float* __restrict__ x, const float* __restrict__ w,
               const float* __restrict__ b, bf16* __restrict__ out)
{
    int row  = blockIdx.x * 4 + (threadIdx.x >> 6);
    int lane = threadIdx.x & 63;
    const float* xr = x + (size_t)row * D_MODEL;

    float2 v[3];
    float s = 0.f, ss = 0.f;
#pragma unroll
    for (int i = 0; i < 3; ++i) {
        v[i] = *(const float2*)(xr + lane * 2 + i * 128);
        s  += v[i].x + v[i].y;
        ss += v[i].x * v[i].x + v[i].y * v[i].y;
    }
#pragma unroll
    for (int off = 32; off; off >>= 1) {
        s  += __shfl_xor(s,  off);
        ss += __shfl_xor(ss, off);
    }
    float mu   = s * (1.f / D_MODEL);
    float var  = ss * (1.f / D_MODEL) - mu * mu;
    float rstd = rsqrtf(var + 1e-5f);

    bf16* orow = out + (size_t)row * D_MODEL;
#pragma unroll
    for (int i = 0; i < 3; ++i) {
        int c = lane * 2 + i * 128;
        float2 wv = *(const float2*)(w + c);
        float2 bv = *(const float2*)(b + c);
        bf16x2 o;
        o[0] = (bf16)((v[i].x - mu) * rstd * wv.x + bv.x);
        o[1] = (bf16)((v[i].y - mu) * rstd * wv.y + bv.y);
        *(bf16x2*)(orow + c) = o;
    }
}

// ---------------------------------------------------------------------------
// GEMM: C[M,N] = A[M,K] @ BT[N,K]^T, bf16, 128x128 tile, BK=64, XCD swizzle.
// EPI 1: +bias +f32 res -> f32.  EPI 2: +bias, fast GELU -> bf16.
// EPI 3: scatter to packed Q/K/V attn layouts (SCALE folded into Q).
// ---------------------------------------------------------------------------
template<int EPI, typename CT>
__global__ __launch_bounds__(256)
void gemm3_kernel(const bf16* __restrict__ A, const bf16* __restrict__ BT,
                  CT* __restrict__ C, const float* __restrict__ bias,
                  const float* __restrict__ res, int nxblk, int Nn, int K,
                  bf16* __restrict__ qp, bf16* __restrict__ kp, bf16* __restrict__ vp)
{
    __shared__ alignas(16) bf16 As[128][64];
    __shared__ alignas(16) bf16 Bs[128][64];

    const int bid  = blockIdx.x;
    const int xcd  = bid & 7;
    const int slot = bid >> 3;
    const int yy   = slot / nxblk;
    const int m0   = (yy * 8 + xcd) * 128;
    const int n0   = (slot - yy * nxblk) * 128;

    const int tid  = threadIdx.x;
    const int w    = tid >> 6;
    const int lane = tid & 63;
    const int quad = lane >> 4;
    const int l16  = lane & 15;

    const int srow = lane >> 3;          // 0..7
    const int scol = (lane & 7) * 8;     // 0..56

    f32x4 acc[4][4] = {};

    for (int kt = 0; kt < K; kt += 64) {
        __syncthreads();
#pragma unroll
        for (int c = 0; c < 4; ++c) {
            const int ch = w * 4 + c;
            gload16(A  + (size_t)(m0 + ch * 8 + srow) * K + kt + scol, &As[ch * 8][0]);
            gload16(BT + (size_t)(n0 + ch * 8 + srow) * K + kt + scol, &Bs[ch * 8][0]);
        }
        __syncthreads();

#pragma unroll
        for (int kk = 0; kk < 2; ++kk) {
            bf16x8 af[4], bfr[4];
#pragma unroll
            for (int mt = 0; mt < 4; ++mt)
                af[mt] = *(const bf16x8*)(&As[(w & 1) * 64 + mt * 16 + l16][kk * 32 + quad * 8]);
#pragma unroll
            for (int nt = 0; nt < 4; ++nt)
                bfr[nt] = *(const bf16x8*)(&Bs[(w >> 1) * 64 + nt * 16 + l16][kk * 32 + quad * 8]);
#pragma unroll
            for (int mt = 0; mt < 4; ++mt)
#pragma unroll
                for (int nt = 0; nt < 4; ++nt)
                    acc[mt][nt] = __builtin_amdgcn_mfma_f32_16x16x32_bf16(
                        af[mt], bfr[nt], acc[mt][nt], 0, 0, 0);
        }
    }

#pragma unroll
    for (int mt = 0; mt < 4; ++mt) {
#pragma unroll
        for (int nt = 0; nt < 4; ++nt) {
            const int c0 = n0 + (w >> 1) * 64 + nt * 16;   // wave-uniform
            const int c  = c0 + l16;
            float bi = (EPI == 1 || EPI == 2) ? bias[c] : 0.f;
#pragma unroll
            for (int r = 0; r < 4; ++r) {
                int row = m0 + (w & 1) * 64 + mt * 16 + quad * 4 + r;
                float v = acc[mt][nt][r] + bi;
                if (EPI == 1) {
                    v += res[(size_t)row * Nn + c];
                    C[(size_t)row * Nn + c] = (CT)v;
                } else if (EPI == 2) {
                    v = fast_gelu(v);
                    C[(size_t)row * Nn + c] = (CT)v;
                } else { // EPI 3: packed QKV scatter
                    int b   = row >> 10, seq = row & 1023;
                    if (c0 < 384) {            // Q (scaled)
                        int h = c / 48, d = c - h * 48;
                        qp[(size_t)(b * 8 + h) * QP_BH + seq * 48 + d] = (bf16)(v * SCALE);
                    } else if (c0 < 768) {     // K
                        int ck = c - 384;
                        int h = ck / 48, d = ck - h * 48;
                        kp[(size_t)(b * 8 + h) * KP_BH + (seq >> 6) * KVT
                           + (seq & 63) * 72 + d] = (bf16)v;
                    } else {                   // V transposed
                        int cv = c - 768;
                        int h = cv / 48, d = cv - h * 48;
                        vp[(size_t)(b * 8 + h) * KP_BH + (seq >> 6) * KVT
                           + d * 72 + (seq & 63)] = (bf16)v;
                    }
                }
            }
        }
    }
}

// ---------------------------------------------------------------------------
// MFMA flash attention v3 (round-0 verified form): 128-query tile per block
// (2 strips/wave), K/V staged from packed layouts via global_load_lds
// (zero DS writes), XCD swizzle groups all q-tiles of one (b,h) on one XCD.
// ---------------------------------------------------------------------------
__global__ __launch_bounds__(256)
void attn_kernel(const bf16* __restrict__ Qp, const bf16* __restrict__ Kp,
                 const bf16* __restrict__ Vp, const float* __restrict__ Btab,
                 bf16* __restrict__ out)
{
    __shared__ alignas(16) bf16 Ks[64][72];        // [key][dh pad64; 48..63 zero]
    __shared__ alignas(16) bf16 Vs[64][72];        // [dh][key]; rows 48..63 ones
    __shared__ alignas(16) bf16 Ps[4][2][16][72];  // [wave][strip][query][key]
    __shared__ alignas(16) float B2f[BTAB_P];

    const int bid  = blockIdx.x;
    const int xcd  = bid & 7;
    const int slot = bid >> 3;
    const int qc   = slot & 7;
    const int bh   = (slot >> 3) * 8 + xcd;        // 0..127
    const int q0   = qc * 128;
    const int tid  = threadIdx.x;
    const int wave = tid >> 6;
    const int lane = tid & 63;
    const int quad = lane >> 4;
    const int l16  = lane & 15;
    const int b    = bh >> 3, h = bh & 7;

    // stage bias table (15888 B) via global_load_lds
    {
        const char* src = (const char*)(Btab + h * BTAB_P);
#pragma unroll
        for (int it = 0; it < 4; ++it) {
            int off = it * 4096 + tid * 16;
            if (off < BTAB_P * 4)
                gload16(src + off, (char*)B2f + it * 4096 + wave * 1024);
        }
    }

    // Q fragments for 2 strips (B-operand), SCALE pre-applied in Qpack
    bf16x8 qf0[2], qf1[2];
    int pi[2];
#pragma unroll
    for (int s = 0; s < 2; ++s) {
        int qrow = q0 + s * 64 + wave * 16 + l16;
        const bf16* qptr = Qp + (size_t)bh * QP_BH + qrow * 48;
        qf0[s] = *(const bf16x8*)(qptr + quad * 8);
#pragma unroll
        for (int c = 0; c < 8; ++c) qf1[s][c] = (bf16)0.f;
        if (quad < 2) qf1[s] = *(const bf16x8*)(qptr + 32 + quad * 8);
        pi[s] = (qrow >> 5) * 63 + (qrow & 31) + 31 * 63 + 31;
    }

    f32x4 o_acc[2][4] = {};   // [strip][0..2 = O dims, 3 = l]

    for (int t = 0; t < 16; ++t) {
        const int n0 = t * 64;
        const bf16* kbase = Kp + (size_t)(bh * 16 + t) * KVT;
        const bf16* vbase = Vp + (size_t)(bh * 16 + t) * KVT;
        __syncthreads();
        for (int i = wave; i < 9; i += 4) {
            gload16(kbase + i * 512 + lane * 8, (bf16*)Ks + i * 512);
            gload16(vbase + i * 512 + lane * 8, (bf16*)Vs + i * 512);
        }
        __syncthreads();

        // S^T = K @ Q^T: D[key=quad*4+r][query=l16], K-frags shared by strips
        f32x4 sa[2][4] = {};
#pragma unroll
        for (int nt = 0; nt < 4; ++nt) {
            bf16x8 a0 = *(const bf16x8*)(&Ks[nt * 16 + l16][quad * 8]);
            bf16x8 a1 = *(const bf16x8*)(&Ks[nt * 16 + l16][32 + quad * 8]);
#pragma unroll
            for (int s = 0; s < 2; ++s) {
                sa[s][nt] = __builtin_amdgcn_mfma_f32_16x16x32_bf16(a0, qf0[s], sa[s][nt], 0, 0, 0);
                sa[s][nt] = __builtin_amdgcn_mfma_f32_16x16x32_bf16(a1, qf1[s], sa[s][nt], 0, 0, 0);
            }
        }

        // p = exp(s + bias - MFIX)
#pragma unroll
        for (int s = 0; s < 2; ++s)
#pragma unroll
            for (int nt = 0; nt < 4; ++nt) {
                const int j0 = n0 + nt * 16 + quad * 4;
                const int ib = pi[s] - ((j0 >> 5) * 63 + (j0 & 31));
                bf16x4 pk;
#pragma unroll
                for (int r = 0; r < 4; ++r)
                    pk[r] = (bf16)__expf(sa[s][nt][r] + B2f[ib - r]);
                *(bf16x4*)(&Ps[wave][s][l16][nt * 16 + quad * 4]) = pk;
            }

        // O += P @ V; V-frags shared by strips; d=3 row accumulates l
#pragma unroll
        for (int kk = 0; kk < 2; ++kk) {
            bf16x8 vf[4];
#pragma unroll
            for (int d = 0; d < 4; ++d)
                vf[d] = *(const bf16x8*)(&Vs[d * 16 + l16][kk * 32 + quad * 8]);
#pragma unroll
            for (int s = 0; s < 2; ++s) {
                bf16x8 pf = *(const bf16x8*)(&Ps[wave][s][l16][kk * 32 + quad * 8]);
#pragma unroll
                for (int d = 0; d < 4; ++d)
                    o_acc[s][d] = __builtin_amdgcn_mfma_f32_16x16x32_bf16(
                        pf, vf[d], o_acc[s][d], 0, 0, 0);
            }
        }
    }

    // epilogue
#pragma unroll
    for (int s = 0; s < 2; ++s)
#pragma unroll
        for (int r = 0; r < 4; ++r) {
            float inv = 1.f / o_acc[s][3][r];
            int row = q0 + s * 64 + wave * 16 + quad * 4 + r;
            bf16* orow = out + ((size_t)b * NSEQ + row) * D_MODEL + h * DH;
#pragma unroll
            for (int d = 0; d < 3; ++d)
                orow[d * 16 + l16] = (bf16)(o_acc[s][d][r] * inv);
        }
}

// ---------------------------------------------------------------------------
extern "C" void kernel_launch(void* const* d_in, const int* in_sizes, int n_in,
                              void* d_out, int out_size, void* d_ws, size_t ws_size,
                              hipStream_t stream)
{
    const float* x          = (const float*)d_in[0];
    const float* ln1_w      = (const float*)d_in[1];
    const float* ln1_b      = (const float*)d_in[2];
    const float* w_qkv      = (const float*)d_in[3];
    const float* bias_table = (const float*)d_in[4];
    const float* w_out      = (const float*)d_in[5];
    const float* b_out      = (const float*)d_in[6];
    const float* ln2_w      = (const float*)d_in[7];
    const float* ln2_b      = (const float*)d_in[8];
    const float* w1         = (const float*)d_in[9];
    const float* b1         = (const float*)d_in[10];
    const float* w2         = (const float*)d_in[11];
    const float* b2         = (const float*)d_in[12];
    float* out = (float*)d_out;

    bf16* regA  = (bf16*)d_ws;                    // 25.17M elems: packs, later gelu
    bf16* Qpack = regA;                           // [128][1024][48]     6.29M
    bf16* Kpack = regA + 6291456;                 // [128][16][64][72]   9.44M
    bf16* Vpack = regA + 15728640;                // [128][16][64][72]   9.44M
    bf16* regB  = regA + (size_t)ROWS * HID;      // [16384][384]
    bf16* wqkvT = regB + (size_t)ROWS * D_MODEL;  // [1152][384]
    bf16* woutT = wqkvT + 1152 * 384;             // [384][384]
    bf16* w1T   = woutT + 384 * 384;              // [1536][384]
    bf16* w2T   = w1T + 1536 * 384;               // [384][1536]
    float* Btab = (float*)(w2T + 384 * 1536);     // [8][3972] f32
    float* x1   = out;                            // residual in d_out (f32)

    bias_prep_kernel<<<(BTAB_N + 255) / 256, 256, 0, stream>>>(bias_table, Btab);
    pack_init_kernel<<<640, 256, 0, stream>>>(Kpack, Vpack);
    wtrans_kernel<<<dim3(1152 / 64, 384 / 64), 256, 0, stream>>>(w_qkv, wqkvT, 384, 1152);
    wtrans_kernel<<<dim3(384 / 64, 384 / 64), 256, 0, stream>>>(w_out, woutT, 384, 384);
    wtrans_kernel<<<dim3(1536 / 64, 384 / 64), 256, 0, stream>>>(w1, w1T, 384, 1536);
    wtrans_kernel<<<dim3(384 / 64, 1536 / 64), 256, 0, stream>>>(w2, w2T, 1536, 384);

    // 1. LN1 -> regB
    ln_kernel<<<ROWS / 4, 256, 0, stream>>>(x, ln1_w, ln1_b, regB);
    // 2. qkv GEMM -> packed Q/K/V (EPI3)
    gemm3_kernel<3, bf16><<<(1152 / 128) * (ROWS / 128), 256, 0, stream>>>(
        regB, wqkvT, (bf16*)nullptr, nullptr, nullptr, 1152 / 128, 1152, D_MODEL,
        Qpack, Kpack, Vpack);
    // 3. attention -> regB
    attn_kernel<<<1024, 256, 0, stream>>>(Qpack, Kpack, Vpack, Btab, regB);
    // 4. x1 = attn @ w_out + b_out + x -> d_out (f32)
    gemm3_kernel<1, float><<<(D_MODEL / 128) * (ROWS / 128), 256, 0, stream>>>(
        regB, woutT, x1, b_out, x, D_MODEL / 128, D_MODEL, D_MODEL,
        nullptr, nullptr, nullptr);
    // 5. LN2 -> regB
    ln_kernel<<<ROWS / 4, 256, 0, stream>>>(x1, ln2_w, ln2_b, regB);
    // 6. gelu(h2 @ w1 + b1) -> regA (packs dead now)
    gemm3_kernel<2, bf16><<<(HID / 128) * (ROWS / 128), 256, 0, stream>>>(
        regB, w1T, regA, b1, nullptr, HID / 128, HID, D_MODEL,
        nullptr, nullptr, nullptr);
    // 7. out = gelu @ w2 + b2 + x1
    gemm3_kernel<1, float><<<(D_MODEL / 128) * (ROWS / 128), 256, 0, stream>>>(
        regA, w2T, out, b2, x1, D_MODEL / 128, D_MODEL, HID,
        nullptr, nullptr, nullptr);
}

// Round 5
// 319.758 us; speedup vs baseline: 1.1493x; 1.0288x over previous
//
#include <hip/hip_runtime.h>
#include <hip/hip_bf16.h>
#include <math.h>

typedef __bf16 bf16;
typedef __bf16 bf16x8 __attribute__((ext_vector_type(8)));
typedef __bf16 bf16x4 __attribute__((ext_vector_type(4)));
typedef __bf16 bf16x2 __attribute__((ext_vector_type(2)));
typedef float  f32x4  __attribute__((ext_vector_type(4)));

#define D_MODEL 384
#define HID     1536
#define NSEQ    1024
#define ROWS    16384
#define HEADS   8
#define DH      48
#define SCALE   0.14433756729740643f // 48^-0.5
#define MFIX    8.0f                 // fixed softmax max (scores bounded ~6.5)
#define BTAB_N  3969                 // 63*63
#define BTAB_P  3972                 // padded to 16B multiple (f32)
// packed KV tile geometry: [64 rows][72 cols] bf16 = 9216 B per tile
#define KVT     4608                 // elems per tile
#define QP_BH   (NSEQ * DH)          // 49152 elems per bh in Qpack
#define KP_BH   (16 * KVT)           // 73728 elems per bh in K/Vpack

__device__ __forceinline__ void gload16(const void* g, void* l) {
    __builtin_amdgcn_global_load_lds((const __attribute__((address_space(1))) void*)g,
                                     (__attribute__((address_space(3))) void*)l, 16, 0, 0);
}

// tanh-form GELU: max |err| vs exact erf-GELU ~1e-3 (below bf16 quantization)
__device__ __forceinline__ float fast_gelu(float x) {
    float u = 0.7978845608f * fmaf(0.044715f * x * x, x, x);
    float e = __expf(2.f * u);
    float t = 1.f - 2.f * __builtin_amdgcn_rcpf(e + 1.f);   // tanh(u)
    return 0.5f * x * (1.f + t);
}

// ---------------------------------------------------------------------------
// Bias prep: Btab[h][idx(dy,dx)] = bias_table[ceil(dist)][h] - MFIX  (f32)
// ---------------------------------------------------------------------------
__global__ __launch_bounds__(256)
void bias_prep_kernel(const float* __restrict__ bias_table, float* __restrict__ Btab)
{
    int idx = blockIdx.x * 256 + threadIdx.x;
    if (idx >= BTAB_N) return;
    int dy = idx / 63 - 31, dx = idx % 63 - 31;
    int s2 = dy * dy + dx * dx;
    int r = (int)ceilf(sqrtf((float)s2));
    while (r * r < s2) ++r;
    while (r > 0 && (r - 1) * (r - 1) >= s2) --r;
#pragma unroll
    for (int h = 0; h < HEADS; ++h)
        Btab[h * BTAB_P + idx] = bias_table[r * HEADS + h] - MFIX;
}

// ---------------------------------------------------------------------------
// Pack init (each launch; ws re-poisoned): zero Kpack pad cols 48..71,
// ones in Vpack rows 48..63 (the l-sum rows).
// ---------------------------------------------------------------------------
__global__ __launch_bounds__(256)
void pack_init_kernel(bf16* __restrict__ Kp, bf16* __restrict__ Vp)
{
    const int bid = blockIdx.x, tid = threadIdx.x;
    if (bid < 512) {                       // 131072 K-rows, pad cols 48..71
        int row = bid * 256 + tid;
        bf16x8 z = {};
        bf16* p = Kp + (size_t)row * 72 + 48;
        *(bf16x8*)(p) = z;  *(bf16x8*)(p + 8) = z;  *(bf16x8*)(p + 16) = z;
    } else {                               // 32768 V ones-rows
        int idx = (bid - 512) * 256 + tid;
        int tile = idx >> 4, rr = idx & 15;
        bf16 o = (bf16)1.f;
        bf16x8 ones = {o, o, o, o, o, o, o, o};
        bf16* p = Vp + (size_t)tile * KVT + (48 + rr) * 72;
#pragma unroll
        for (int c = 0; c < 9; ++c) *(bf16x8*)(p + c * 8) = ones;
    }
}

// ---------------------------------------------------------------------------
// Weight prep: out[n][k] = (bf16)in[k][n].
// ---------------------------------------------------------------------------
__global__ __launch_bounds__(256)
void wtrans_kernel(const float* __restrict__ in, bf16* __restrict__ out, int K, int N)
{
    __shared__ float T[64][65];
    const int k0 = blockIdx.y * 64, n0 = blockIdx.x * 64;
    const int rr = threadIdx.x >> 4, rc = threadIdx.x & 15;
#pragma unroll
    for (int i = 0; i < 4; ++i) {
        float4 v = *(const float4*)(in + (size_t)(k0 + rr + i * 16) * N + n0 + rc * 4);
        T[rr + i * 16][rc * 4 + 0] = v.x;  T[rr + i * 16][rc * 4 + 1] = v.y;
        T[rr + i * 16][rc * 4 + 2] = v.z;  T[rr + i * 16][rc * 4 + 3] = v.w;
    }
    __syncthreads();
#pragma unroll
    for (int i = 0; i < 4; ++i) {
        int n = rr + i * 16, kc = rc * 4;
        bf16x4 o;
        o[0] = (bf16)T[kc + 0][n];  o[1] = (bf16)T[kc + 1][n];
        o[2] = (bf16)T[kc + 2][n];  o[3] = (bf16)T[kc + 3][n];
        *(bf16x4*)(out + (size_t)(n0 + n) * K + k0 + kc) = o;
    }
}

// ---------------------------------------------------------------------------
// LayerNorm: 4 rows per 256-thread block, one wave per row of 384.
// float2 (8B/lane) vectorized loads, bf16x2 stores. f32 in -> bf16 out.
// ---------------------------------------------------------------------------
__global__ __launch_bounds__(256)
void ln_kernel(const float* __restrict__ x, const float* __restrict__ w,
               const float* __restrict__ b, bf16* __restrict__ out)
{
    int row  = blockIdx.x * 4 + (threadIdx.x >> 6);
    int lane = threadIdx.x & 63;
    const float* xr = x + (size_t)row * D_MODEL;

    float2 v[3];
    float s = 0.f, ss = 0.f;
#pragma unroll
    for (int i = 0; i < 3; ++i) {
        v[i] = *(const float2*)(xr + lane * 2 + i * 128);
        s  += v[i].x + v[i].y;
        ss += v[i].x * v[i].x + v[i].y * v[i].y;
    }
#pragma unroll
    for (int off = 32; off; off >>= 1) {
        s  += __shfl_xor(s,  off);
        ss += __shfl_xor(ss, off);
    }
    float mu   = s * (1.f / D_MODEL);
    float var  = ss * (1.f / D_MODEL) - mu * mu;
    float rstd = rsqrtf(var + 1e-5f);

    bf16* orow = out + (size_t)row * D_MODEL;
#pragma unroll
    for (int i = 0; i < 3; ++i) {
        int c = lane * 2 + i * 128;
        float2 wv = *(const float2*)(w + c);
        float2 bv = *(const float2*)(b + c);
        bf16x2 o;
        o[0] = (bf16)((v[i].x - mu) * rstd * wv.x + bv.x);
        o[1] = (bf16)((v[i].y - mu) * rstd * wv.y + bv.y);
        *(bf16x2*)(orow + c) = o;
    }
}

// ---------------------------------------------------------------------------
// GEMM: C[M,N] = A[M,K] @ BT[N,K]^T, bf16, 128x128 tile, BK=64, XCD swizzle.
// EPI 1: +bias +f32 res -> f32.  EPI 2: +bias, fast GELU -> bf16.
// EPI 3: scatter to packed Q/K/V attn layouts (SCALE folded into Q).
// ---------------------------------------------------------------------------
template<int EPI, typename CT>
__global__ __launch_bounds__(256)
void gemm3_kernel(const bf16* __restrict__ A, const bf16* __restrict__ BT,
                  CT* __restrict__ C, const float* __restrict__ bias,
                  const float* __restrict__ res, int nxblk, int Nn, int K,
                  bf16* __restrict__ qp, bf16* __restrict__ kp, bf16* __restrict__ vp)
{
    __shared__ alignas(16) bf16 As[128][64];
    __shared__ alignas(16) bf16 Bs[128][64];

    const int bid  = blockIdx.x;
    const int xcd  = bid & 7;
    const int slot = bid >> 3;
    const int yy   = slot / nxblk;
    const int m0   = (yy * 8 + xcd) * 128;
    const int n0   = (slot - yy * nxblk) * 128;

    const int tid  = threadIdx.x;
    const int w    = tid >> 6;
    const int lane = tid & 63;
    const int quad = lane >> 4;
    const int l16  = lane & 15;

    const int srow = lane >> 3;          // 0..7
    const int scol = (lane & 7) * 8;     // 0..56

    f32x4 acc[4][4] = {};

    for (int kt = 0; kt < K; kt += 64) {
        __syncthreads();
#pragma unroll
        for (int c = 0; c < 4; ++c) {
            const int ch = w * 4 + c;
            gload16(A  + (size_t)(m0 + ch * 8 + srow) * K + kt + scol, &As[ch * 8][0]);
            gload16(BT + (size_t)(n0 + ch * 8 + srow) * K + kt + scol, &Bs[ch * 8][0]);
        }
        __syncthreads();

#pragma unroll
        for (int kk = 0; kk < 2; ++kk) {
            bf16x8 af[4], bfr[4];
#pragma unroll
            for (int mt = 0; mt < 4; ++mt)
                af[mt] = *(const bf16x8*)(&As[(w & 1) * 64 + mt * 16 + l16][kk * 32 + quad * 8]);
#pragma unroll
            for (int nt = 0; nt < 4; ++nt)
                bfr[nt] = *(const bf16x8*)(&Bs[(w >> 1) * 64 + nt * 16 + l16][kk * 32 + quad * 8]);
#pragma unroll
            for (int mt = 0; mt < 4; ++mt)
#pragma unroll
                for (int nt = 0; nt < 4; ++nt)
                    acc[mt][nt] = __builtin_amdgcn_mfma_f32_16x16x32_bf16(
                        af[mt], bfr[nt], acc[mt][nt], 0, 0, 0);
        }
    }

#pragma unroll
    for (int mt = 0; mt < 4; ++mt) {
#pragma unroll
        for (int nt = 0; nt < 4; ++nt) {
            const int c0 = n0 + (w >> 1) * 64 + nt * 16;   // wave-uniform
            const int c  = c0 + l16;
            float bi = (EPI == 1 || EPI == 2) ? bias[c] : 0.f;
#pragma unroll
            for (int r = 0; r < 4; ++r) {
                int row = m0 + (w & 1) * 64 + mt * 16 + quad * 4 + r;
                float v = acc[mt][nt][r] + bi;
                if (EPI == 1) {
                    v += res[(size_t)row * Nn + c];
                    C[(size_t)row * Nn + c] = (CT)v;
                } else if (EPI == 2) {
                    v = fast_gelu(v);
                    C[(size_t)row * Nn + c] = (CT)v;
                } else { // EPI 3: packed QKV scatter
                    int b   = row >> 10, seq = row & 1023;
                    if (c0 < 384) {            // Q (scaled)
                        int h = c / 48, d = c - h * 48;
                        qp[(size_t)(b * 8 + h) * QP_BH + seq * 48 + d] = (bf16)(v * SCALE);
                    } else if (c0 < 768) {     // K
                        int ck = c - 384;
                        int h = ck / 48, d = ck - h * 48;
                        kp[(size_t)(b * 8 + h) * KP_BH + (seq >> 6) * KVT
                           + (seq & 63) * 72 + d] = (bf16)v;
                    } else {                   // V transposed
                        int cv = c - 768;
                        int h = cv / 48, d = cv - h * 48;
                        vp[(size_t)(b * 8 + h) * KP_BH + (seq >> 6) * KVT
                           + d * 72 + (seq & 63)] = (bf16)v;
                    }
                }
            }
        }
    }
}

// ---------------------------------------------------------------------------
// MFMA flash attention v7: SAME per-wave dataflow as the verified round-0/4
// kernel; block widened to 8 waves / 256 q-rows. Grid 512 = exactly
// 2 blocks/CU co-resident (zero tail round), 16 waves/CU, and K/V + bias
// staging amortized over twice the queries.
// ---------------------------------------------------------------------------
__global__ __launch_bounds__(512)
void attn_kernel(const bf16* __restrict__ Qp, const bf16* __restrict__ Kp,
                 const bf16* __restrict__ Vp, const float* __restrict__ Btab,
                 bf16* __restrict__ out)
{
    __shared__ alignas(16) bf16 Ks[64][72];        // [key][dh pad64; 48..63 zero]
    __shared__ alignas(16) bf16 Vs[64][72];        // [dh][key]; rows 48..63 ones
    __shared__ alignas(16) bf16 Ps[8][2][16][72];  // [wave][strip][query][key]
    __shared__ alignas(16) float B2f[BTAB_P];

    const int bid  = blockIdx.x;
    const int xcd  = bid & 7;
    const int slot = bid >> 3;                     // 0..63
    const int qc   = slot & 3;                     // 4 q-blocks of 256 rows
    const int bh   = (slot >> 2) * 8 + xcd;        // 0..127, all qc of bh on one XCD
    const int q0   = qc * 256;
    const int tid  = threadIdx.x;
    const int wave = tid >> 6;                     // 0..7
    const int lane = tid & 63;
    const int quad = lane >> 4;
    const int l16  = lane & 15;
    const int b    = bh >> 3, h = bh & 7;

    // stage bias table (15888 B) via global_load_lds (512 threads -> 2 passes)
    {
        const char* src = (const char*)(Btab + h * BTAB_P);
#pragma unroll
        for (int it = 0; it < 2; ++it) {
            int off = it * 8192 + tid * 16;
            if (off < BTAB_P * 4)
                gload16(src + off, (char*)B2f + it * 8192 + wave * 1024);
        }
    }

    // Q fragments for 2 strips (B-operand), SCALE pre-applied in Qpack
    bf16x8 qf0[2], qf1[2];
    int pi[2];
#pragma unroll
    for (int s = 0; s < 2; ++s) {
        int qrow = q0 + s * 128 + wave * 16 + l16;
        const bf16* qptr = Qp + (size_t)bh * QP_BH + qrow * 48;
        qf0[s] = *(const bf16x8*)(qptr + quad * 8);
#pragma unroll
        for (int c = 0; c < 8; ++c) qf1[s][c] = (bf16)0.f;
        if (quad < 2) qf1[s] = *(const bf16x8*)(qptr + 32 + quad * 8);
        pi[s] = (qrow >> 5) * 63 + (qrow & 31) + 31 * 63 + 31;
    }

    f32x4 o_acc[2][4] = {};   // [strip][0..2 = O dims, 3 = l]

    for (int t = 0; t < 16; ++t) {
        const int n0 = t * 64;
        const bf16* kbase = Kp + (size_t)(bh * 16 + t) * KVT;
        const bf16* vbase = Vp + (size_t)(bh * 16 + t) * KVT;
        __syncthreads();
        for (int i = wave; i < 9; i += 8) {
            gload16(kbase + i * 512 + lane * 8, (bf16*)Ks + i * 512);
            gload16(vbase + i * 512 + lane * 8, (bf16*)Vs + i * 512);
        }
        __syncthreads();

        // S^T = K @ Q^T: D[key=quad*4+r][query=l16], K-frags shared by strips
        f32x4 sa[2][4] = {};
#pragma unroll
        for (int nt = 0; nt < 4; ++nt) {
            bf16x8 a0 = *(const bf16x8*)(&Ks[nt * 16 + l16][quad * 8]);
            bf16x8 a1 = *(const bf16x8*)(&Ks[nt * 16 + l16][32 + quad * 8]);
#pragma unroll
            for (int s = 0; s < 2; ++s) {
                sa[s][nt] = __builtin_amdgcn_mfma_f32_16x16x32_bf16(a0, qf0[s], sa[s][nt], 0, 0, 0);
                sa[s][nt] = __builtin_amdgcn_mfma_f32_16x16x32_bf16(a1, qf1[s], sa[s][nt], 0, 0, 0);
            }
        }

        // p = exp(s + bias - MFIX)
#pragma unroll
        for (int s = 0; s < 2; ++s)
#pragma unroll
            for (int nt = 0; nt < 4; ++nt) {
                const int j0 = n0 + nt * 16 + quad * 4;
                const int ib = pi[s] - ((j0 >> 5) * 63 + (j0 & 31));
                bf16x4 pk;
#pragma unroll
                for (int r = 0; r < 4; ++r)
                    pk[r] = (bf16)__expf(sa[s][nt][r] + B2f[ib - r]);
                *(bf16x4*)(&Ps[wave][s][l16][nt * 16 + quad * 4]) = pk;
            }

        // O += P @ V; V-frags shared by strips; d=3 row accumulates l
#pragma unroll
        for (int kk = 0; kk < 2; ++kk) {
            bf16x8 vf[4];
#pragma unroll
            for (int d = 0; d < 4; ++d)
                vf[d] = *(const bf16x8*)(&Vs[d * 16 + l16][kk * 32 + quad * 8]);
#pragma unroll
            for (int s = 0; s < 2; ++s) {
                bf16x8 pf = *(const bf16x8*)(&Ps[wave][s][l16][kk * 32 + quad * 8]);
#pragma unroll
                for (int d = 0; d < 4; ++d)
                    o_acc[s][d] = __builtin_amdgcn_mfma_f32_16x16x32_bf16(
                        pf, vf[d], o_acc[s][d], 0, 0, 0);
            }
        }
    }

    // epilogue
#pragma unroll
    for (int s = 0; s < 2; ++s)
#pragma unroll
        for (int r = 0; r < 4; ++r) {
            float inv = 1.f / o_acc[s][3][r];
            int row = q0 + s * 128 + wave * 16 + quad * 4 + r;
            bf16* orow = out + ((size_t)b * NSEQ + row) * D_MODEL + h * DH;
#pragma unroll
            for (int d = 0; d < 3; ++d)
                orow[d * 16 + l16] = (bf16)(o_acc[s][d][r] * inv);
        }
}

// ---------------------------------------------------------------------------
extern "C" void kernel_launch(void* const* d_in, const int* in_sizes, int n_in,
                              void* d_out, int out_size, void* d_ws, size_t ws_size,
                              hipStream_t stream)
{
    const float* x          = (const float*)d_in[0];
    const float* ln1_w      = (const float*)d_in[1];
    const float* ln1_b      = (const float*)d_in[2];
    const float* w_qkv      = (const float*)d_in[3];
    const float* bias_table = (const float*)d_in[4];
    const float* w_out      = (const float*)d_in[5];
    const float* b_out      = (const float*)d_in[6];
    const float* ln2_w      = (const float*)d_in[7];
    const float* ln2_b      = (const float*)d_in[8];
    const float* w1         = (const float*)d_in[9];
    const float* b1         = (const float*)d_in[10];
    const float* w2         = (const float*)d_in[11];
    const float* b2         = (const float*)d_in[12];
    float* out = (float*)d_out;

    bf16* regA  = (bf16*)d_ws;                    // 25.17M elems: packs, later gelu
    bf16* Qpack = regA;                           // [128][1024][48]     6.29M
    bf16* Kpack = regA + 6291456;                 // [128][16][64][72]   9.44M
    bf16* Vpack = regA + 15728640;                // [128][16][64][72]   9.44M
    bf16* regB  = regA + (size_t)ROWS * HID;      // [16384][384]
    bf16* wqkvT = regB + (size_t)ROWS * D_MODEL;  // [1152][384]
    bf16* woutT = wqkvT + 1152 * 384;             // [384][384]
    bf16* w1T   = woutT + 384 * 384;              // [1536][384]
    bf16* w2T   = w1T + 1536 * 384;               // [384][1536]
    float* Btab = (float*)(w2T + 384 * 1536);     // [8][3972] f32
    float* x1   = out;                            // residual in d_out (f32)

    bias_prep_kernel<<<(BTAB_N + 255) / 256, 256, 0, stream>>>(bias_table, Btab);
    pack_init_kernel<<<640, 256, 0, stream>>>(Kpack, Vpack);
    wtrans_kernel<<<dim3(1152 / 64, 384 / 64), 256, 0, stream>>>(w_qkv, wqkvT, 384, 1152);
    wtrans_kernel<<<dim3(384 / 64, 384 / 64), 256, 0, stream>>>(w_out, woutT, 384, 384);
    wtrans_kernel<<<dim3(1536 / 64, 384 / 64), 256, 0, stream>>>(w1, w1T, 384, 1536);
    wtrans_kernel<<<dim3(384 / 64, 1536 / 64), 256, 0, stream>>>(w2, w2T, 1536, 384);

    // 1. LN1 -> regB
    ln_kernel<<<ROWS / 4, 256, 0, stream>>>(x, ln1_w, ln1_b, regB);
    // 2. qkv GEMM -> packed Q/K/V (EPI3)
    gemm3_kernel<3, bf16><<<(1152 / 128) * (ROWS / 128), 256, 0, stream>>>(
        regB, wqkvT, (bf16*)nullptr, nullptr, nullptr, 1152 / 128, 1152, D_MODEL,
        Qpack, Kpack, Vpack);
    // 3. attention -> regB  (512 blocks x 512 threads; 2 blocks/CU exactly)
    attn_kernel<<<512, 512, 0, stream>>>(Qpack, Kpack, Vpack, Btab, regB);
    // 4. x1 = attn @ w_out + b_out + x -> d_out (f32)
    gemm3_kernel<1, float><<<(D_MODEL / 128) * (ROWS / 128), 256, 0, stream>>>(
        regB, woutT, x1, b_out, x, D_MODEL / 128, D_MODEL, D_MODEL,
        nullptr, nullptr, nullptr);
    // 5. LN2 -> regB
    ln_kernel<<<ROWS / 4, 256, 0, stream>>>(x1, ln2_w, ln2_b, regB);
    // 6. gelu(h2 @ w1 + b1) -> regA (packs dead now)
    gemm3_kernel<2, bf16><<<(HID / 128) * (ROWS / 128), 256, 0, stream>>>(
        regB, w1T, regA, b1, nullptr, HID / 128, HID, D_MODEL,
        nullptr, nullptr, nullptr);
    // 7. out = gelu @ w2 + b2 + x1
    gemm3_kernel<1, float><<<(D_MODEL / 128) * (ROWS / 128), 256, 0, stream>>>(
        regA, w2T, out, b2, x1, D_MODEL / 128, D_MODEL, HID,
        nullptr, nullptr, nullptr);
}

// Round 6
// 307.902 us; speedup vs baseline: 1.1935x; 1.0385x over previous
//
#include <hip/hip_runtime.h>
#include <hip/hip_bf16.h>
#include <math.h>

typedef __bf16 bf16;
typedef __bf16 bf16x8 __attribute__((ext_vector_type(8)));
typedef __bf16 bf16x4 __attribute__((ext_vector_type(4)));
typedef __bf16 bf16x2 __attribute__((ext_vector_type(2)));
typedef float  f32x4  __attribute__((ext_vector_type(4)));

#define D_MODEL 384
#define HID     1536
#define NSEQ    1024
#define ROWS    16384
#define HEADS   8
#define DH      48
#define SCALE   0.14433756729740643f // 48^-0.5
#define MFIX    8.0f                 // fixed softmax max (scores bounded ~6.5)
// bias table compressed by dist(dy,dx)=dist(-dy,dx): [|dy| 0..31][dx+31 0..62]
#define BT2_N   2016                 // 32*63 entries per head, f32
// packed KV tile geometry: [64 rows][72 cols] bf16 = 9216 B per tile
#define KVT     4608                 // elems per tile
#define QP_BH   (NSEQ * DH)          // 49152 elems per bh in Qpack
#define KP_BH   (16 * KVT)           // 73728 elems per bh in K/Vpack

__device__ __forceinline__ void gload16(const void* g, void* l) {
    __builtin_amdgcn_global_load_lds((const __attribute__((address_space(1))) void*)g,
                                     (__attribute__((address_space(3))) void*)l, 16, 0, 0);
}

// tanh-form GELU: max |err| vs exact erf-GELU ~1e-3 (below bf16 quantization)
__device__ __forceinline__ float fast_gelu(float x) {
    float u = 0.7978845608f * fmaf(0.044715f * x * x, x, x);
    float e = __expf(2.f * u);
    float t = 1.f - 2.f * __builtin_amdgcn_rcpf(e + 1.f);   // tanh(u)
    return 0.5f * x * (1.f + t);
}

// ---------------------------------------------------------------------------
// Mega prep kernel: blockIdx-switched fusion of
//   [0,432)      wtrans x4 (w_qkv, w_out, w1, w2)
//   [432,1072)   pack_init (Kpack pad cols, Vpack ones-rows)
//   [1072,1080)  bias_prep (compressed |dy| table, f32, -MFIX folded)
//   [1080,5176)  LN1 (x -> regB bf16)
// ---------------------------------------------------------------------------
__device__ __forceinline__ void wtrans_body(const float* __restrict__ in,
                                            bf16* __restrict__ out, int K, int N,
                                            int bx, int by, float (*T)[65])
{
    const int k0 = by * 64, n0 = bx * 64;
    const int rr = threadIdx.x >> 4, rc = threadIdx.x & 15;
#pragma unroll
    for (int i = 0; i < 4; ++i) {
        float4 v = *(const float4*)(in + (size_t)(k0 + rr + i * 16) * N + n0 + rc * 4);
        T[rr + i * 16][rc * 4 + 0] = v.x;  T[rr + i * 16][rc * 4 + 1] = v.y;
        T[rr + i * 16][rc * 4 + 2] = v.z;  T[rr + i * 16][rc * 4 + 3] = v.w;
    }
    __syncthreads();
#pragma unroll
    for (int i = 0; i < 4; ++i) {
        int n = rr + i * 16, kc = rc * 4;
        bf16x4 o;
        o[0] = (bf16)T[kc + 0][n];  o[1] = (bf16)T[kc + 1][n];
        o[2] = (bf16)T[kc + 2][n];  o[3] = (bf16)T[kc + 3][n];
        *(bf16x4*)(out + (size_t)(n0 + n) * K + k0 + kc) = o;
    }
}

__device__ __forceinline__ void ln_body(const float* __restrict__ x,
                                        const float* __restrict__ w,
                                        const float* __restrict__ b,
                                        bf16* __restrict__ out, int blk)
{
    int row  = blk * 4 + ((int)threadIdx.x >> 6);
    int lane = threadIdx.x & 63;
    const float* xr = x + (size_t)row * D_MODEL;

    float2 v[3];
    float s = 0.f, ss = 0.f;
#pragma unroll
    for (int i = 0; i < 3; ++i) {
        v[i] = *(const float2*)(xr + lane * 2 + i * 128);
        s  += v[i].x + v[i].y;
        ss += v[i].x * v[i].x + v[i].y * v[i].y;
    }
#pragma unroll
    for (int off = 32; off; off >>= 1) {
        s  += __shfl_xor(s,  off);
        ss += __shfl_xor(ss, off);
    }
    float mu   = s * (1.f / D_MODEL);
    float var  = ss * (1.f / D_MODEL) - mu * mu;
    float rstd = rsqrtf(var + 1e-5f);

    bf16* orow = out + (size_t)row * D_MODEL;
#pragma unroll
    for (int i = 0; i < 3; ++i) {
        int c = lane * 2 + i * 128;
        float2 wv = *(const float2*)(w + c);
        float2 bv = *(const float2*)(b + c);
        bf16x2 o;
        o[0] = (bf16)((v[i].x - mu) * rstd * wv.x + bv.x);
        o[1] = (bf16)((v[i].y - mu) * rstd * wv.y + bv.y);
        *(bf16x2*)(orow + c) = o;
    }
}

__global__ __launch_bounds__(256)
void prep_kernel(const float* __restrict__ w_qkv, const float* __restrict__ w_out,
                 const float* __restrict__ w1, const float* __restrict__ w2,
                 bf16* __restrict__ wqkvT, bf16* __restrict__ woutT,
                 bf16* __restrict__ w1T, bf16* __restrict__ w2T,
                 bf16* __restrict__ Kp, bf16* __restrict__ Vp,
                 const float* __restrict__ bias_table, float* __restrict__ Btab,
                 const float* __restrict__ x, const float* __restrict__ ln1_w,
                 const float* __restrict__ ln1_b, bf16* __restrict__ regB)
{
    __shared__ float T[64][65];
    const int bid = blockIdx.x, tid = threadIdx.x;

    if (bid < 432) {                       // ---- weight transposes
        const float* in; bf16* outp; int K, N, nx, local;
        if (bid < 108)      { in = w_qkv; outp = wqkvT; K = 384;  N = 1152; local = bid;       nx = 18; }
        else if (bid < 144) { in = w_out; outp = woutT; K = 384;  N = 384;  local = bid - 108; nx = 6;  }
        else if (bid < 288) { in = w1;    outp = w1T;   K = 384;  N = 1536; local = bid - 144; nx = 24; }
        else                { in = w2;    outp = w2T;   K = 1536; N = 384;  local = bid - 288; nx = 6;  }
        wtrans_body(in, outp, K, N, local % nx, local / nx, T);
    } else if (bid < 1072) {               // ---- pack init
        const int pb = bid - 432;
        if (pb < 512) {                    // 131072 K-rows, pad cols 48..71
            int row = pb * 256 + tid;
            bf16x8 z = {};
            bf16* p = Kp + (size_t)row * 72 + 48;
            *(bf16x8*)(p) = z;  *(bf16x8*)(p + 8) = z;  *(bf16x8*)(p + 16) = z;
        } else {                           // 32768 V ones-rows
            int idx = (pb - 512) * 256 + tid;
            int tile = idx >> 4, rr = idx & 15;
            bf16 o = (bf16)1.f;
            bf16x8 ones = {o, o, o, o, o, o, o, o};
            bf16* p = Vp + (size_t)tile * KVT + (48 + rr) * 72;
#pragma unroll
            for (int c = 0; c < 9; ++c) *(bf16x8*)(p + c * 8) = ones;
        }
    } else if (bid < 1080) {               // ---- bias prep (compressed, f32)
        int idx = (bid - 1072) * 256 + tid;
        if (idx < BT2_N) {
            int dy = idx / 63, dx = idx % 63 - 31;
            int s2 = dy * dy + dx * dx;
            int r = (int)ceilf(sqrtf((float)s2));
            while (r * r < s2) ++r;
            while (r > 0 && (r - 1) * (r - 1) >= s2) --r;
#pragma unroll
            for (int h = 0; h < HEADS; ++h)
                Btab[h * BT2_N + idx] = bias_table[r * HEADS + h] - MFIX;
        }
    } else {                               // ---- LN1
        ln_body(x, ln1_w, ln1_b, regB, bid - 1080);
    }
}

// ---------------------------------------------------------------------------
// LayerNorm standalone (LN2): 4 rows per 256-thread block.
// ---------------------------------------------------------------------------
__global__ __launch_bounds__(256)
void ln_kernel(const float* __restrict__ x, const float* __restrict__ w,
               const float* __restrict__ b, bf16* __restrict__ out)
{
    ln_body(x, w, b, out, blockIdx.x);
}

// ---------------------------------------------------------------------------
// GEMM: C[M,N] = A[M,K] @ BT[N,K]^T, bf16, 128x128 tile, BK=64, XCD swizzle.
// EPI 1: +bias +f32 res -> f32.  EPI 2: +bias, fast GELU -> bf16.
// EPI 3: scatter to packed Q/K/V attn layouts (SCALE folded into Q).
// ---------------------------------------------------------------------------
template<int EPI, typename CT>
__global__ __launch_bounds__(256)
void gemm3_kernel(const bf16* __restrict__ A, const bf16* __restrict__ BT,
                  CT* __restrict__ C, const float* __restrict__ bias,
                  const float* __restrict__ res, int nxblk, int Nn, int K,
                  bf16* __restrict__ qp, bf16* __restrict__ kp, bf16* __restrict__ vp)
{
    __shared__ alignas(16) bf16 As[128][64];
    __shared__ alignas(16) bf16 Bs[128][64];

    const int bid  = blockIdx.x;
    const int xcd  = bid & 7;
    const int slot = bid >> 3;
    const int yy   = slot / nxblk;
    const int m0   = (yy * 8 + xcd) * 128;
    const int n0   = (slot - yy * nxblk) * 128;

    const int tid  = threadIdx.x;
    const int w    = tid >> 6;
    const int lane = tid & 63;
    const int quad = lane >> 4;
    const int l16  = lane & 15;

    const int srow = lane >> 3;          // 0..7
    const int scol = (lane & 7) * 8;     // 0..56

    f32x4 acc[4][4] = {};

    for (int kt = 0; kt < K; kt += 64) {
        __syncthreads();
#pragma unroll
        for (int c = 0; c < 4; ++c) {
            const int ch = w * 4 + c;
            gload16(A  + (size_t)(m0 + ch * 8 + srow) * K + kt + scol, &As[ch * 8][0]);
            gload16(BT + (size_t)(n0 + ch * 8 + srow) * K + kt + scol, &Bs[ch * 8][0]);
        }
        __syncthreads();

#pragma unroll
        for (int kk = 0; kk < 2; ++kk) {
            bf16x8 af[4], bfr[4];
#pragma unroll
            for (int mt = 0; mt < 4; ++mt)
                af[mt] = *(const bf16x8*)(&As[(w & 1) * 64 + mt * 16 + l16][kk * 32 + quad * 8]);
#pragma unroll
            for (int nt = 0; nt < 4; ++nt)
                bfr[nt] = *(const bf16x8*)(&Bs[(w >> 1) * 64 + nt * 16 + l16][kk * 32 + quad * 8]);
#pragma unroll
            for (int mt = 0; mt < 4; ++mt)
#pragma unroll
                for (int nt = 0; nt < 4; ++nt)
                    acc[mt][nt] = __builtin_amdgcn_mfma_f32_16x16x32_bf16(
                        af[mt], bfr[nt], acc[mt][nt], 0, 0, 0);
        }
    }

#pragma unroll
    for (int mt = 0; mt < 4; ++mt) {
#pragma unroll
        for (int nt = 0; nt < 4; ++nt) {
            const int c0 = n0 + (w >> 1) * 64 + nt * 16;   // wave-uniform
            const int c  = c0 + l16;
            float bi = (EPI == 1 || EPI == 2) ? bias[c] : 0.f;
#pragma unroll
            for (int r = 0; r < 4; ++r) {
                int row = m0 + (w & 1) * 64 + mt * 16 + quad * 4 + r;
                float v = acc[mt][nt][r] + bi;
                if (EPI == 1) {
                    v += res[(size_t)row * Nn + c];
                    C[(size_t)row * Nn + c] = (CT)v;
                } else if (EPI == 2) {
                    v = fast_gelu(v);
                    C[(size_t)row * Nn + c] = (CT)v;
                } else { // EPI 3: packed QKV scatter
                    int b   = row >> 10, seq = row & 1023;
                    if (c0 < 384) {            // Q (scaled)
                        int h = c / 48, d = c - h * 48;
                        qp[(size_t)(b * 8 + h) * QP_BH + seq * 48 + d] = (bf16)(v * SCALE);
                    } else if (c0 < 768) {     // K
                        int ck = c - 384;
                        int h = ck / 48, d = ck - h * 48;
                        kp[(size_t)(b * 8 + h) * KP_BH + (seq >> 6) * KVT
                           + (seq & 63) * 72 + d] = (bf16)v;
                    } else {                   // V transposed
                        int cv = c - 768;
                        int h = cv / 48, d = cv - h * 48;
                        vp[(size_t)(b * 8 + h) * KP_BH + (seq >> 6) * KVT
                           + d * 72 + (seq & 63)] = (bf16)v;
                    }
                }
            }
        }
    }
}

// ---------------------------------------------------------------------------
// MFMA flash attention v8: 8 waves / 256 q-rows per block (verified v7 wave
// dataflow); TWO 64-key tiles staged per barrier pair (KVBLK=128) to halve
// the per-tile vmcnt(0)+barrier drains. Bias table compressed via |dy|
// symmetry to 2016 f32 (8064 B) so LDS = 81792 B -> still 2 blocks/CU.
// Inner 64-key body is byte-identical to the verified round-0 form.
// ---------------------------------------------------------------------------
__global__ __launch_bounds__(512)
void attn_kernel(const bf16* __restrict__ Qp, const bf16* __restrict__ Kp,
                 const bf16* __restrict__ Vp, const float* __restrict__ Btab,
                 bf16* __restrict__ out)
{
    __shared__ alignas(16) bf16 Ks[128][72];       // 2 tiles [key][dh pad64]
    __shared__ alignas(16) bf16 Vs[2][64][72];     // 2 tiles [dh][key]; rows 48..63 ones
    __shared__ alignas(16) bf16 Ps[8][2][16][72];  // [wave][strip][query][key]
    __shared__ alignas(16) float B2f[BT2_N];       // compressed bias, f32

    const int bid  = blockIdx.x;
    const int xcd  = bid & 7;
    const int slot = bid >> 3;                     // 0..63
    const int qc   = slot & 3;                     // 4 q-blocks of 256 rows
    const int bh   = (slot >> 2) * 8 + xcd;        // 0..127, all qc of bh on one XCD
    const int q0   = qc * 256;
    const int tid  = threadIdx.x;
    const int wave = tid >> 6;                     // 0..7
    const int lane = tid & 63;
    const int quad = lane >> 4;
    const int l16  = lane & 15;
    const int b    = bh >> 3, h = bh & 7;

    // stage compressed bias table (8064 B): one gload16 for threads 0..503
    {
        const char* src = (const char*)(Btab + (size_t)h * BT2_N);
        int off = tid * 16;
        if (off < BT2_N * 4)
            gload16(src + off, (char*)B2f + wave * 1024);
    }

    // Q fragments for 2 strips (B-operand), SCALE pre-applied in Qpack
    bf16x8 qf0[2], qf1[2];
    int qy[2], qxp[2];
#pragma unroll
    for (int s = 0; s < 2; ++s) {
        int qrow = q0 + s * 128 + wave * 16 + l16;
        const bf16* qptr = Qp + (size_t)bh * QP_BH + qrow * 48;
        qf0[s] = *(const bf16x8*)(qptr + quad * 8);
#pragma unroll
        for (int c = 0; c < 8; ++c) qf1[s][c] = (bf16)0.f;
        if (quad < 2) qf1[s] = *(const bf16x8*)(qptr + 32 + quad * 8);
        qy[s]  = qrow >> 5;
        qxp[s] = (qrow & 31) + 31;
    }

    f32x4 o_acc[2][4] = {};   // [strip][0..2 = O dims, 3 = l]

    for (int t = 0; t < 8; ++t) {
        // two consecutive tiles are contiguous in the packed layouts
        const bf16* kbase = Kp + (size_t)(bh * 16 + 2 * t) * KVT;
        const bf16* vbase = Vp + (size_t)(bh * 16 + 2 * t) * KVT;
        __syncthreads();
        for (int i = wave; i < 18; i += 8) {
            gload16(kbase + i * 512 + lane * 8, (bf16*)Ks + i * 512);
            gload16(vbase + i * 512 + lane * 8, (bf16*)&Vs[0][0][0] + i * 512);
        }
        __syncthreads();

#pragma unroll
        for (int hf = 0; hf < 2; ++hf) {
            const int n0 = t * 128 + hf * 64;

            // S^T = K @ Q^T: D[key=quad*4+r][query=l16], K-frags shared by strips
            f32x4 sa[2][4] = {};
#pragma unroll
            for (int nt = 0; nt < 4; ++nt) {
                bf16x8 a0 = *(const bf16x8*)(&Ks[hf * 64 + nt * 16 + l16][quad * 8]);
                bf16x8 a1 = *(const bf16x8*)(&Ks[hf * 64 + nt * 16 + l16][32 + quad * 8]);
#pragma unroll
                for (int s = 0; s < 2; ++s) {
                    sa[s][nt] = __builtin_amdgcn_mfma_f32_16x16x32_bf16(a0, qf0[s], sa[s][nt], 0, 0, 0);
                    sa[s][nt] = __builtin_amdgcn_mfma_f32_16x16x32_bf16(a1, qf1[s], sa[s][nt], 0, 0, 0);
                }
            }

            // p = exp(s + bias - MFIX), |dy|-folded table index
#pragma unroll
            for (int s = 0; s < 2; ++s)
#pragma unroll
                for (int nt = 0; nt < 4; ++nt) {
                    const int j0 = n0 + nt * 16 + quad * 4;
                    int dy  = qy[s] - (j0 >> 5);
                    int iay = dy < 0 ? -dy : dy;
                    const int ib0 = iay * 63 + qxp[s] - (j0 & 31);
                    bf16x4 pk;
#pragma unroll
                    for (int r = 0; r < 4; ++r)
                        pk[r] = (bf16)__expf(sa[s][nt][r] + B2f[ib0 - r]);
                    *(bf16x4*)(&Ps[wave][s][l16][nt * 16 + quad * 4]) = pk;
                }

            // O += P @ V; V-frags shared by strips; d=3 row accumulates l
#pragma unroll
            for (int kk = 0; kk < 2; ++kk) {
                bf16x8 vf[4];
#pragma unroll
                for (int d = 0; d < 4; ++d)
                    vf[d] = *(const bf16x8*)(&Vs[hf][d * 16 + l16][kk * 32 + quad * 8]);
#pragma unroll
                for (int s = 0; s < 2; ++s) {
                    bf16x8 pf = *(const bf16x8*)(&Ps[wave][s][l16][kk * 32 + quad * 8]);
#pragma unroll
                    for (int d = 0; d < 4; ++d)
                        o_acc[s][d] = __builtin_amdgcn_mfma_f32_16x16x32_bf16(
                            pf, vf[d], o_acc[s][d], 0, 0, 0);
                }
            }
        }
    }

    // epilogue
#pragma unroll
    for (int s = 0; s < 2; ++s)
#pragma unroll
        for (int r = 0; r < 4; ++r) {
            float inv = 1.f / o_acc[s][3][r];
            int row = q0 + s * 128 + wave * 16 + quad * 4 + r;
            bf16* orow = out + ((size_t)b * NSEQ + row) * D_MODEL + h * DH;
#pragma unroll
            for (int d = 0; d < 3; ++d)
                orow[d * 16 + l16] = (bf16)(o_acc[s][d][r] * inv);
        }
}

// ---------------------------------------------------------------------------
extern "C" void kernel_launch(void* const* d_in, const int* in_sizes, int n_in,
                              void* d_out, int out_size, void* d_ws, size_t ws_size,
                              hipStream_t stream)
{
    const float* x          = (const float*)d_in[0];
    const float* ln1_w      = (const float*)d_in[1];
    const float* ln1_b      = (const float*)d_in[2];
    const float* w_qkv      = (const float*)d_in[3];
    const float* bias_table = (const float*)d_in[4];
    const float* w_out      = (const float*)d_in[5];
    const float* b_out      = (const float*)d_in[6];
    const float* ln2_w      = (const float*)d_in[7];
    const float* ln2_b      = (const float*)d_in[8];
    const float* w1         = (const float*)d_in[9];
    const float* b1         = (const float*)d_in[10];
    const float* w2         = (const float*)d_in[11];
    const float* b2         = (const float*)d_in[12];
    float* out = (float*)d_out;

    bf16* regA  = (bf16*)d_ws;                    // 25.17M elems: packs, later gelu
    bf16* Qpack = regA;                           // [128][1024][48]     6.29M
    bf16* Kpack = regA + 6291456;                 // [128][16][64][72]   9.44M
    bf16* Vpack = regA + 15728640;                // [128][16][64][72]   9.44M
    bf16* regB  = regA + (size_t)ROWS * HID;      // [16384][384]
    bf16* wqkvT = regB + (size_t)ROWS * D_MODEL;  // [1152][384]
    bf16* woutT = wqkvT + 1152 * 384;             // [384][384]
    bf16* w1T   = woutT + 384 * 384;              // [1536][384]
    bf16* w2T   = w1T + 1536 * 384;               // [384][1536]
    float* Btab = (float*)(w2T + 384 * 1536);     // [8][2016] f32 compressed
    float* x1   = out;                            // residual in d_out (f32)

    // 0. fused prep: wtrans x4 + pack_init + bias_prep + LN1
    prep_kernel<<<5176, 256, 0, stream>>>(
        w_qkv, w_out, w1, w2, wqkvT, woutT, w1T, w2T,
        Kpack, Vpack, bias_table, Btab, x, ln1_w, ln1_b, regB);
    // 2. qkv GEMM -> packed Q/K/V (EPI3)
    gemm3_kernel<3, bf16><<<(1152 / 128) * (ROWS / 128), 256, 0, stream>>>(
        regB, wqkvT, (bf16*)nullptr, nullptr, nullptr, 1152 / 128, 1152, D_MODEL,
        Qpack, Kpack, Vpack);
    // 3. attention -> regB  (512 blocks x 512 threads; 2 blocks/CU exactly)
    attn_kernel<<<512, 512, 0, stream>>>(Qpack, Kpack, Vpack, Btab, regB);
    // 4. x1 = attn @ w_out + b_out + x -> d_out (f32)
    gemm3_kernel<1, float><<<(D_MODEL / 128) * (ROWS / 128), 256, 0, stream>>>(
        regB, woutT, x1, b_out, x, D_MODEL / 128, D_MODEL, D_MODEL,
        nullptr, nullptr, nullptr);
    // 5. LN2 -> regB
    ln_kernel<<<ROWS / 4, 256, 0, stream>>>(x1, ln2_w, ln2_b, regB);
    // 6. gelu(h2 @ w1 + b1) -> regA (packs dead now)
    gemm3_kernel<2, bf16><<<(HID / 128) * (ROWS / 128), 256, 0, stream>>>(
        regB, w1T, regA, b1, nullptr, HID / 128, HID, D_MODEL,
        nullptr, nullptr, nullptr);
    // 7. out = gelu @ w2 + b2 + x1
    gemm3_kernel<1, float><<<(D_MODEL / 128) * (ROWS / 128), 256, 0, stream>>>(
        regA, w2T, out, b2, x1, D_MODEL / 128, D_MODEL, HID,
        nullptr, nullptr, nullptr);
}